// Round 5
// baseline (758.654 us; speedup 1.0000x reference)
//
#include <hip/hip_runtime.h>
#include <stdint.h>

// out[n,o] = sum_{d,i} q[n,d] x[n,i] W1[d,i,o] + (q @ b1)[n,o]
// GEMM M=4096 N=256 K=16384 (k=d*256+i), fp16 MFMA 32x32x16, fp32 accum.
// A-frag = x-frag (LDS) * q[row,d] per-lane scalar.
// R5: MBLK=256 (intensity 128 FLOP/B, W traffic 128 MB), 512-thr blocks,
// 8 waves x 32-col disjoint W slices. K-loop uses RAW s_barrier + manual
// s_waitcnt vmcnt(2/4): prefetch depth-2 W ring (3x16K) + x dbuf (2x16K),
// prefetches never drained at barriers (AITER-style, vmcnt never 0).

typedef _Float16 f16;
typedef f16 f16x8 __attribute__((ext_vector_type(8)));
typedef float f32x16 __attribute__((ext_vector_type(16)));

#define NROWS 4096
#define QDIM 64
#define SPLIT 16
#define MBLK 256
#define MBCNT 16   // 4096/256

__device__ __forceinline__ void gl_lds16(const void* g, void* s) {
  __builtin_amdgcn_global_load_lds(
      (const __attribute__((address_space(1))) void*)(uintptr_t)g,
      (__attribute__((address_space(3))) void*)(uint32_t)(uintptr_t)s,
      16, 0, 0);
}

// Wt chunk g = sg*32 + ic*4 + dd (d = sg*4+dd), chunk = 16 KB:
//   unit u = (s*2+h)*256 + n  holds  W1[(d*256 + ic*32 + s*16 + h*8 + j)*256 + n]
// Xt slice (mb,ic) = 16 KB: unit u = (s*2+h)*256 + row holds
//   x[mb*256+row][ic*32 + s*16 + h*8 + j]
// prep grid 1152: [0,512) W cvt | [512,640) x cvt | [640,1152) bias-init out
__global__ __launch_bounds__(256) void prep(const float* __restrict__ W,
                                            const float* __restrict__ X,
                                            const float* __restrict__ Q,
                                            const float* __restrict__ B1,
                                            f16* __restrict__ Wt,
                                            f16* __restrict__ Xt,
                                            float* __restrict__ out) {
  __shared__ float qs[512];
  const int b = blockIdx.x;
  const int t = threadIdx.x;
  if (b < 512) {
    const int d = b >> 3, ic = b & 7;
    const int g = ((d >> 2) << 5) + (ic << 2) + (d & 3);
    const int k0 = d * 256 + (ic << 5);
#pragma unroll
    for (int r = 0; r < 4; ++r) {
      const int gidx = (r << 8) + t;  // (s*2+h)*256 + n
      const int n = gidx & 255;
      const int sh = gidx >> 8;
      f16x8 h;
#pragma unroll
      for (int j = 0; j < 8; ++j)
        h[j] = (f16)W[(size_t)(k0 + (sh << 3) + j) * 256 + n];  // coalesced over n
      *(f16x8*)(Wt + (size_t)g * 8192 + (size_t)gidx * 8) = h;
    }
  } else if (b < 640) {
    // x slices: slice = mb*8+ic; unit u = r*256 + t -> s2h=r, row=t
    const int slice = b - 512;
    const int mb = slice >> 3, ic = slice & 7;
#pragma unroll
    for (int r = 0; r < 4; ++r) {
      const float* src = X + (size_t)((mb << 8) + t) * 256 + (ic << 5) + (r << 3);
      float4 a = *(const float4*)src;
      float4 c = *(const float4*)(src + 4);
      f16x8 h;
      h[0] = (f16)a.x; h[1] = (f16)a.y; h[2] = (f16)a.z; h[3] = (f16)a.w;
      h[4] = (f16)c.x; h[5] = (f16)c.y; h[6] = (f16)c.z; h[7] = (f16)c.w;
      *(f16x8*)(Xt + (size_t)slice * 8192 + (size_t)((r << 8) + t) * 8) = h;
    }
  } else {
    // bias-init: out[n0+r][t] = sum_d q[n0+r][d] * b1[d][t]   (8 rows/block)
    const int n0 = (b - 640) << 3;
    qs[t] = Q[(size_t)n0 * QDIM + t];
    qs[256 + t] = Q[(size_t)n0 * QDIM + 256 + t];
    __syncthreads();
    float a8[8] = {0.f, 0.f, 0.f, 0.f, 0.f, 0.f, 0.f, 0.f};
#pragma unroll 4
    for (int d = 0; d < 64; ++d) {
      const float bv = B1[d * 256 + t];
#pragma unroll
      for (int r = 0; r < 8; ++r) a8[r] += qs[(r << 6) + d] * bv;
    }
#pragma unroll
    for (int r = 0; r < 8; ++r) out[(size_t)(n0 + r) * 256 + t] = a8[r];
  }
}

// ---- main GEMM: 256 blocks = 16 sg x 16 mb, 512 threads (8 waves) ----
// wave wv owns cols [wv*32, wv*32+32); per-window (1 chunk) W staged coop,
// read via disjoint per-wave slices. 32 windows, barrier each, vmcnt(2/4).
__global__ __launch_bounds__(512, 2) void mlp_main(const float* __restrict__ Q,
                                                   const f16* __restrict__ Wt,
                                                   const f16* __restrict__ Xt,
                                                   float* __restrict__ out) {
  __shared__ f16 s_w3[3][8192];  // W ring: 3 x 16 KB (depth-2 prefetch)
  __shared__ f16 s_x2[2][8192];  // x slices: 2 x 16 KB (per-ic dbuf)

  const int bid = blockIdx.x;
  const int sg = bid & 15;   // XCD x hosts sgs {x, x+8}: 2x512 KB W in its L2
  const int mb = bid >> 4;
  const int t = threadIdx.x;
  const int wv = t >> 6;
  const int l31 = t & 31;
  const int hf = (t >> 5) & 1;

  const char* wg = (const char*)Wt + (size_t)sg * 32 * 16384;
  const char* xg = (const char*)Xt + (size_t)(mb << 3) * 16384;

  // prologue: stage W[0]->ring0, W[1]->ring1, x[0]->s_x2[0]  (6 gl_lds/thread)
#pragma unroll
  for (int i = 0; i < 2; ++i) {
    const int off = (i << 13) + (t << 4);
    gl_lds16(wg + off, (char*)s_w3[0] + off);
    gl_lds16(wg + 16384 + off, (char*)s_w3[1] + off);
    gl_lds16(xg + off, (char*)s_x2[0] + off);
  }

  // per-lane q scalars: q[mb*256 + mt*32 + l31][sg*4 + dd]
  f16 qr[8][4];
#pragma unroll
  for (int mt = 0; mt < 8; ++mt) {
    float4 qv = *(const float4*)(Q + (size_t)((mb << 8) + (mt << 5) + l31) * QDIM + (sg << 2));
    qr[mt][0] = (f16)qv.x; qr[mt][1] = (f16)qv.y;
    qr[mt][2] = (f16)qv.z; qr[mt][3] = (f16)qv.w;
  }

  f32x16 acc[8];
#pragma unroll
  for (int a = 0; a < 8; ++a)
#pragma unroll
    for (int r = 0; r < 16; ++r) acc[a][r] = 0.f;

  asm volatile("s_waitcnt vmcnt(0)\n\ts_barrier" ::: "memory");

  const int fo = (hf << 12) + (wv << 9) + (l31 << 4);  // W frag byte (s=0)
  const int xo = (hf << 12) + (l31 << 4);              // x frag byte (s=0, mt=0)

  for (int ic = 0; ic < 8; ++ic) {
    const char* xb = (const char*)s_x2[ic & 1];
    f16x8 xf[2][8];  // x-frags for this ic, live across 4 windows
#pragma unroll
    for (int s = 0; s < 2; ++s)
#pragma unroll
      for (int mt = 0; mt < 8; ++mt)
        xf[s][mt] = *(const f16x8*)(xb + (s << 13) + (mt << 9) + xo);
#pragma unroll
    for (int dd = 0; dd < 4; ++dd) {
      const int v = (ic << 2) + dd;       // window = chunk index
      const int c2 = (v + 2) & 31;        // wrap: harmless redundant re-stage
      char* wdst = (char*)s_w3[(v + 2) % 3];
#pragma unroll
      for (int i = 0; i < 2; ++i) {
        const int off = (i << 13) + (t << 4);
        gl_lds16(wg + ((size_t)c2 << 14) + off, wdst + off);
      }
      if (dd == 0) {  // stage x[ic+1] (2 instrs), 4-window lead time
        const int nic = (ic < 7) ? ic + 1 : 7;
        char* xdst = (char*)s_x2[(ic + 1) & 1];
#pragma unroll
        for (int i = 0; i < 2; ++i) {
          const int off = (i << 13) + (t << 4);
          gl_lds16(xg + ((size_t)nic << 14) + off, xdst + off);
        }
      }
      const char* wb = (const char*)s_w3[v % 3];
      f16x8 wf0 = *(const f16x8*)(wb + fo);
      f16x8 wf1 = *(const f16x8*)(wb + (1 << 13) + fo);
#pragma unroll
      for (int mt = 0; mt < 8; ++mt) {
        f16x8 a0 = xf[0][mt] * qr[mt][dd];
        acc[mt] = __builtin_amdgcn_mfma_f32_32x32x16_f16(a0, wf0, acc[mt], 0, 0, 0);
      }
#pragma unroll
      for (int mt = 0; mt < 8; ++mt) {
        f16x8 a1 = xf[1][mt] * qr[mt][dd];
        acc[mt] = __builtin_amdgcn_mfma_f32_32x32x16_f16(a1, wf1, acc[mt], 0, 0, 0);
      }
      // drain previous window's stages only; keep this window's in flight
      if (dd == 0)
        asm volatile("s_waitcnt vmcnt(4)\n\ts_barrier" ::: "memory");
      else
        asm volatile("s_waitcnt vmcnt(2)\n\ts_barrier" ::: "memory");
    }
  }

  asm volatile("s_waitcnt vmcnt(0)" ::: "memory");  // drain strays before end

  // epilogue: atomic split-K accumulate onto bias-initialized out.
  // C/D (32x32): col = lane&31, row = (reg&3) + 8*(reg>>2) + 4*(lane>>5)
#pragma unroll
  for (int mt = 0; mt < 8; ++mt) {
#pragma unroll
    for (int r = 0; r < 16; ++r) {
      const int row = (mb << 8) + (mt << 5) + (r & 3) + ((r >> 2) << 3) + (hf << 2);
      const int col = (wv << 5) + l31;
      atomicAdd(out + (size_t)row * 256 + col, acc[mt][r]);
    }
  }
}

extern "C" void kernel_launch(void* const* d_in, const int* in_sizes, int n_in,
                              void* d_out, int out_size, void* d_ws, size_t ws_size,
                              hipStream_t stream) {
  (void)in_sizes; (void)n_in; (void)out_size; (void)ws_size;
  const float* x  = (const float*)d_in[0];   // [4096,256]
  const float* q  = (const float*)d_in[1];   // [4096,64]
  const float* W1 = (const float*)d_in[2];   // [64,256,256]
  const float* b1 = (const float*)d_in[3];   // [64,256]
  float* out = (float*)d_out;                // [4096,256] fp32

  // ws: Wt 512 chunks x 16 KB = 8 MB | Xt 128 slices x 16 KB = 2 MB
  f16* Wt = (f16*)d_ws;
  f16* Xt = (f16*)((char*)d_ws + (size_t)512 * 16384);

  prep<<<1152, 256, 0, stream>>>(W1, x, q, b1, Wt, Xt, out);
  mlp_main<<<MBCNT * SPLIT, 512, 0, stream>>>(q, Wt, Xt, out);
}

// Round 6
// 157.445 us; speedup vs baseline: 4.8185x; 4.8185x over previous
//
#include <hip/hip_runtime.h>
#include <stdint.h>

// out[n,o] = sum_{d,i} q[n,d] x[n,i] W1[d,i,o] + (q @ b1)[n,o]
// GEMM M=4096 N=256 K=16384 (k=d*256+i), fp16 MFMA 32x32x16, fp32 accum.
// A-frag = x-frag (LDS) * q[row,d] per-lane scalar.
// R6 = R5 structure with the spill fixed:
//   __launch_bounds__(512, 1) -> 256 VGPR/wave (R5's (512,2) capped at 128
//   and spilled acc -> 1.2 GB scratch traffic).
//   Waves split 2(M)x4(N): acc[4][2]=128 VGPR, xf[2][4]=32, wf 16 -> ~210.
// MBLK=256 (128 FLOP/B, W traffic 128 MB), window pipeline: depth-2 W ring
// (3x16K) + x dbuf (2x16K), raw s_barrier + s_waitcnt vmcnt(2/4) -- prefetches
// never drained at barriers (vmcnt never 0).

typedef _Float16 f16;
typedef f16 f16x8 __attribute__((ext_vector_type(8)));
typedef float f32x16 __attribute__((ext_vector_type(16)));

#define NROWS 4096
#define QDIM 64
#define SPLIT 16
#define MBLK 256
#define MBCNT 16   // 4096/256

__device__ __forceinline__ void gl_lds16(const void* g, void* s) {
  __builtin_amdgcn_global_load_lds(
      (const __attribute__((address_space(1))) void*)(uintptr_t)g,
      (__attribute__((address_space(3))) void*)(uint32_t)(uintptr_t)s,
      16, 0, 0);
}

// Wt chunk g = sg*32 + ic*4 + dd (d = sg*4+dd), chunk = 16 KB:
//   unit u = (s*2+h)*256 + n  holds  W1[(d*256 + ic*32 + s*16 + h*8 + j)*256 + n]
// Xt slice (mb,ic) = 16 KB: unit u = (s*2+h)*256 + row holds
//   x[mb*256+row][ic*32 + s*16 + h*8 + j]
// prep grid 1152: [0,512) W cvt | [512,640) x cvt | [640,1152) bias-init out
__global__ __launch_bounds__(256) void prep(const float* __restrict__ W,
                                            const float* __restrict__ X,
                                            const float* __restrict__ Q,
                                            const float* __restrict__ B1,
                                            f16* __restrict__ Wt,
                                            f16* __restrict__ Xt,
                                            float* __restrict__ out) {
  __shared__ float qs[512];
  const int b = blockIdx.x;
  const int t = threadIdx.x;
  if (b < 512) {
    const int d = b >> 3, ic = b & 7;
    const int g = ((d >> 2) << 5) + (ic << 2) + (d & 3);
    const int k0 = d * 256 + (ic << 5);
#pragma unroll
    for (int r = 0; r < 4; ++r) {
      const int gidx = (r << 8) + t;  // (s*2+h)*256 + n
      const int n = gidx & 255;
      const int sh = gidx >> 8;
      f16x8 h;
#pragma unroll
      for (int j = 0; j < 8; ++j)
        h[j] = (f16)W[(size_t)(k0 + (sh << 3) + j) * 256 + n];  // coalesced over n
      *(f16x8*)(Wt + (size_t)g * 8192 + (size_t)gidx * 8) = h;
    }
  } else if (b < 640) {
    // x slices: slice = mb*8+ic; unit u = r*256 + t -> s2h=r, row=t
    const int slice = b - 512;
    const int mb = slice >> 3, ic = slice & 7;
#pragma unroll
    for (int r = 0; r < 4; ++r) {
      const float* src = X + (size_t)((mb << 8) + t) * 256 + (ic << 5) + (r << 3);
      float4 a = *(const float4*)src;
      float4 c = *(const float4*)(src + 4);
      f16x8 h;
      h[0] = (f16)a.x; h[1] = (f16)a.y; h[2] = (f16)a.z; h[3] = (f16)a.w;
      h[4] = (f16)c.x; h[5] = (f16)c.y; h[6] = (f16)c.z; h[7] = (f16)c.w;
      *(f16x8*)(Xt + (size_t)slice * 8192 + (size_t)((r << 8) + t) * 8) = h;
    }
  } else {
    // bias-init: out[n0+r][t] = sum_d q[n0+r][d] * b1[d][t]   (8 rows/block)
    const int n0 = (b - 640) << 3;
    qs[t] = Q[(size_t)n0 * QDIM + t];
    qs[256 + t] = Q[(size_t)n0 * QDIM + 256 + t];
    __syncthreads();
    float a8[8] = {0.f, 0.f, 0.f, 0.f, 0.f, 0.f, 0.f, 0.f};
#pragma unroll 4
    for (int d = 0; d < 64; ++d) {
      const float bv = B1[d * 256 + t];
#pragma unroll
      for (int r = 0; r < 8; ++r) a8[r] += qs[(r << 6) + d] * bv;
    }
#pragma unroll
    for (int r = 0; r < 8; ++r) out[(size_t)(n0 + r) * 256 + t] = a8[r];
  }
}

// ---- main GEMM: 256 blocks = 16 sg x 16 mb, 512 threads (8 waves, 2Mx4N) ----
// wave (wm,wn): rows [wm*128,+128), cols [wn*64,+64). 32 windows (ic8 x dd4),
// per window: coop-stage W[v+2] (16 KB), compute 16 MFMA/wave from ring[v%3].
__global__ __launch_bounds__(512, 1) void mlp_main(const float* __restrict__ Q,
                                                   const f16* __restrict__ Wt,
                                                   const f16* __restrict__ Xt,
                                                   float* __restrict__ out) {
  __shared__ f16 s_w3[3][8192];  // W ring: 3 x 16 KB (depth-2 prefetch)
  __shared__ f16 s_x2[2][8192];  // x slices: 2 x 16 KB (per-ic dbuf)

  const int bid = blockIdx.x;
  const int sg = bid & 15;   // XCD x hosts sgs {x, x+8}: 2x512 KB W in its L2
  const int mb = bid >> 4;
  const int t = threadIdx.x;
  const int wv = t >> 6;
  const int wn = wv & 3;         // N quarter
  const int wm = wv >> 2;        // M half
  const int l31 = t & 31;
  const int hf = (t >> 5) & 1;

  const char* wg = (const char*)Wt + (size_t)sg * 32 * 16384;
  const char* xg = (const char*)Xt + (size_t)(mb << 3) * 16384;

  // prologue: stage W[0]->ring0, W[1]->ring1, x[0]->s_x2[0]
#pragma unroll
  for (int i = 0; i < 2; ++i) {
    const int off = (i << 13) + (t << 4);
    gl_lds16(wg + off, (char*)s_w3[0] + off);
    gl_lds16(wg + 16384 + off, (char*)s_w3[1] + off);
    gl_lds16(xg + off, (char*)s_x2[0] + off);
  }

  // per-lane q scalars: q[mb*256 + wm*128 + mt*32 + l31][sg*4 + dd]
  f16 qr[4][4];
#pragma unroll
  for (int mt = 0; mt < 4; ++mt) {
    float4 qv = *(const float4*)(Q +
        (size_t)((mb << 8) + (wm << 7) + (mt << 5) + l31) * QDIM + (sg << 2));
    qr[mt][0] = (f16)qv.x; qr[mt][1] = (f16)qv.y;
    qr[mt][2] = (f16)qv.z; qr[mt][3] = (f16)qv.w;
  }

  f32x16 acc[4][2];
#pragma unroll
  for (int a = 0; a < 4; ++a)
#pragma unroll
    for (int bq = 0; bq < 2; ++bq)
#pragma unroll
      for (int r = 0; r < 16; ++r) acc[a][bq][r] = 0.f;

  asm volatile("s_waitcnt vmcnt(0)\n\ts_barrier" ::: "memory");

  const int fo = (hf << 12) + (wn << 10) + (l31 << 4);  // W frag byte (s=0,nt=0)
  const int xo = (hf << 12) + (wm << 11) + (l31 << 4);  // x frag byte (s=0,mt=0)

  for (int ic = 0; ic < 8; ++ic) {
    const char* xb = (const char*)s_x2[ic & 1];
    f16x8 xf[2][4];  // x-frags for this ic (this wave's 4 mt), live 4 windows
#pragma unroll
    for (int s = 0; s < 2; ++s)
#pragma unroll
      for (int mt = 0; mt < 4; ++mt)
        xf[s][mt] = *(const f16x8*)(xb + (s << 13) + (mt << 9) + xo);
#pragma unroll
    for (int dd = 0; dd < 4; ++dd) {
      const int v = (ic << 2) + dd;       // window = chunk index
      const int c2 = (v + 2) & 31;        // wrap: harmless redundant re-stage
      char* wdst = (char*)s_w3[(v + 2) % 3];
#pragma unroll
      for (int i = 0; i < 2; ++i) {
        const int off = (i << 13) + (t << 4);
        gl_lds16(wg + ((size_t)c2 << 14) + off, wdst + off);
      }
      if (dd == 0) {  // stage x[ic+1] (2 instrs), 4-window lead time
        const int nic = (ic < 7) ? ic + 1 : 7;
        char* xdst = (char*)s_x2[(ic + 1) & 1];
#pragma unroll
        for (int i = 0; i < 2; ++i) {
          const int off = (i << 13) + (t << 4);
          gl_lds16(xg + ((size_t)nic << 14) + off, xdst + off);
        }
      }
      const char* wb = (const char*)s_w3[v % 3];
#pragma unroll
      for (int s = 0; s < 2; ++s) {
        const f16x8 wf0 = *(const f16x8*)(wb + (s << 13) + fo);
        const f16x8 wf1 = *(const f16x8*)(wb + (s << 13) + fo + (1 << 9));
#pragma unroll
        for (int mt = 0; mt < 4; ++mt) {
          const f16x8 a = xf[s][mt] * qr[mt][dd];
          acc[mt][0] = __builtin_amdgcn_mfma_f32_32x32x16_f16(a, wf0, acc[mt][0], 0, 0, 0);
          acc[mt][1] = __builtin_amdgcn_mfma_f32_32x32x16_f16(a, wf1, acc[mt][1], 0, 0, 0);
        }
      }
      // drain previous window's stages only; keep this window's in flight
      if (dd == 0)
        asm volatile("s_waitcnt vmcnt(4)\n\ts_barrier" ::: "memory");
      else
        asm volatile("s_waitcnt vmcnt(2)\n\ts_barrier" ::: "memory");
    }
  }

  asm volatile("s_waitcnt vmcnt(0)" ::: "memory");  // drain strays before end

  // epilogue: atomic split-K accumulate onto bias-initialized out.
  // C/D (32x32): col = lane&31, row = (reg&3) + 8*(reg>>2) + 4*(lane>>5)
#pragma unroll
  for (int mt = 0; mt < 4; ++mt) {
#pragma unroll
    for (int nt = 0; nt < 2; ++nt) {
#pragma unroll
      for (int r = 0; r < 16; ++r) {
        const int row = (mb << 8) + (wm << 7) + (mt << 5) +
                        (r & 3) + ((r >> 2) << 3) + (hf << 2);
        const int col = (wn << 6) + (nt << 5) + l31;
        atomicAdd(out + (size_t)row * 256 + col, acc[mt][nt][r]);
      }
    }
  }
}

extern "C" void kernel_launch(void* const* d_in, const int* in_sizes, int n_in,
                              void* d_out, int out_size, void* d_ws, size_t ws_size,
                              hipStream_t stream) {
  (void)in_sizes; (void)n_in; (void)out_size; (void)ws_size;
  const float* x  = (const float*)d_in[0];   // [4096,256]
  const float* q  = (const float*)d_in[1];   // [4096,64]
  const float* W1 = (const float*)d_in[2];   // [64,256,256]
  const float* b1 = (const float*)d_in[3];   // [64,256]
  float* out = (float*)d_out;                // [4096,256] fp32

  // ws: Wt 512 chunks x 16 KB = 8 MB | Xt 128 slices x 16 KB = 2 MB
  f16* Wt = (f16*)d_ws;
  f16* Xt = (f16*)((char*)d_ws + (size_t)512 * 16384);

  prep<<<1152, 256, 0, stream>>>(W1, x, q, b1, Wt, Xt, out);
  mlp_main<<<MBCNT * SPLIT, 512, 0, stream>>>(q, Wt, Xt, out);
}